// Round 1
// baseline (557.567 us; speedup 1.0000x reference)
//
#include <hip/hip_runtime.h>

namespace {

constexpr int Hh = 32;     // heads
constexpr int Ss = 4096;   // seq len
constexpr int HP = 64;     // p (head dim)
constexpr int HN = 64;     // n (state dim)
constexpr int NCHUNK = 64; // chunks of 64
constexpr int SB = 68;     // LDS row stride for 64-wide arrays (16B-aligned rows, breaks 32-bank stride)
constexpr int SX = 36;     // LDS row stride for 32-wide arrays

// One block = (batch, head, half-of-p). Walks 64 chunks sequentially keeping the
// running inter-chunk state S[n][p/2] in LDS (transposed). 256 threads, ~72KB LDS.
__global__ __launch_bounds__(256)
void ssd_fused(const float* __restrict__ Xg0, const float* __restrict__ Ag0,
               const float* __restrict__ Bg0, const float* __restrict__ Cg0,
               float* __restrict__ Yg0) {
  __shared__ __align__(16) float Cs [64 * SB]; // C[l][n] row-major
  __shared__ __align__(16) float BsT[64 * SB]; // B transposed: BsT[n][l]
  __shared__ __align__(16) float Gs [64 * SB]; // G[l][s] row-major
  __shared__ __align__(16) float Xs [64 * SX]; // X[l][p] (32 p's)
  __shared__ __align__(16) float SsT[64 * SX]; // running state, S^T[n][p]
  __shared__ __align__(16) float el [64];      // exp(Acum[l])
  __shared__ __align__(16) float iel[64];      // exp(-Acum[l])
  __shared__ __align__(16) float dl [64];      // exp(Atot - Acum[l])

  const int tid = threadIdx.x;
  const int blk = blockIdx.x;
  const int ph  = blk & 1;          // which half of p
  const int hi  = (blk >> 1) & (Hh - 1);
  const int bi  = blk >> 6;

  const float* Xg = Xg0 + ((size_t)bi * Ss * Hh + hi) * HP + ph * 32;
  const float* Bg = Bg0 + ((size_t)bi * Ss * Hh + hi) * HN;
  const float* Cg = Cg0 + ((size_t)bi * Ss * Hh + hi) * HN;
  const float* Ag = Ag0 + (size_t)bi * Ss * Hh + hi;
  float*       Yg = Yg0 + ((size_t)bi * Ss * Hh + hi) * HP + ph * 32;

  for (int i = tid; i < 64 * SX; i += 256) SsT[i] = 0.f;  // S_in[chunk 0] = 0

  const int tn = tid & 15;   // phase A: s-tile (4 wide)  | phase B/C: p-tile (2 wide)
  const int tm = tid >> 4;   // phase A: l-tile (4 wide)  | phase B: l-tile / phase C: n-tile (4 wide)

  for (int ci = 0; ci < NCHUNK; ++ci) {
    // ---- A cumsum (wave 0 only; uniform branch) ----
    if (tid < 64) {
      float a = Ag[(size_t)(ci * 64 + tid) * Hh];
      #pragma unroll
      for (int off = 1; off < 64; off <<= 1) {
        float v = __shfl_up(a, off);
        if (tid >= off) a += v;
      }
      const float atot = __shfl(a, 63);
      el[tid]  = __expf(a);
      iel[tid] = __expf(-a);
      dl[tid]  = __expf(atot - a);
    }
    // ---- stage B (transposed), C, X into LDS ----
    const size_t rowB = (size_t)ci * 64;
    #pragma unroll
    for (int j = 0; j < 4; ++j) {
      const int idx = tid + j * 256;          // 0..1023 -> 64 rows x 16 float4
      const int r = idx >> 4, c4 = (idx & 15) * 4;
      const float4 bv = *(const float4*)(Bg + (rowB + r) * (Hh * HN) + c4);
      BsT[(c4 + 0) * SB + r] = bv.x;
      BsT[(c4 + 1) * SB + r] = bv.y;
      BsT[(c4 + 2) * SB + r] = bv.z;
      BsT[(c4 + 3) * SB + r] = bv.w;
      const float4 cv = *(const float4*)(Cg + (rowB + r) * (Hh * HN) + c4);
      *(float4*)&Cs[r * SB + c4] = cv;
    }
    #pragma unroll
    for (int j = 0; j < 2; ++j) {
      const int idx = tid + j * 256;          // 0..511 -> 64 rows x 8 float4
      const int r = idx >> 3, c4 = (idx & 7) * 4;
      *(float4*)&Xs[r * SX + c4] = *(const float4*)(Xg + (rowB + r) * (Hh * HP) + c4);
    }
    __syncthreads();

    // ---- phase A: G[l][s] = tril(C·B^T)[l][s] * exp(Acum[l]-Acum[s]) ----
    {
      float acc[4][4] = {};
      #pragma unroll 2
      for (int k = 0; k < 64; k += 4) {
        float4 cv[4], bv[4];
        #pragma unroll
        for (int i = 0; i < 4; ++i)  cv[i] = *(const float4*)&Cs[(tm * 4 + i) * SB + k];
        #pragma unroll
        for (int kk = 0; kk < 4; ++kk) bv[kk] = *(const float4*)&BsT[(k + kk) * SB + tn * 4];
        #pragma unroll
        for (int kk = 0; kk < 4; ++kk)
          #pragma unroll
          for (int i = 0; i < 4; ++i) {
            const float cvv = ((const float*)&cv[i])[kk];
            #pragma unroll
            for (int j = 0; j < 4; ++j)
              acc[i][j] += cvv * ((const float*)&bv[kk])[j];
          }
      }
      #pragma unroll
      for (int i = 0; i < 4; ++i) {
        const int l = tm * 4 + i;
        const float eli = el[l];
        float4 g;
        #pragma unroll
        for (int j = 0; j < 4; ++j) {
          const int s2 = tn * 4 + j;
          ((float*)&g)[j] = (s2 <= l) ? acc[i][j] * eli * iel[s2] : 0.f;
        }
        *(float4*)&Gs[l * SB + tn * 4] = g;
      }
    }
    __syncthreads();

    // ---- phase B: Y[l][p] = sum_s G[l][s]X[s][p] + el[l]*sum_n C[l][n]S[p][n] ----
    {
      float accD[4][2] = {}, accO[4][2] = {};
      #pragma unroll 2
      for (int k = 0; k < 64; k += 4) {
        float2 xv[4], sv[4];
        #pragma unroll
        for (int kk = 0; kk < 4; ++kk) {
          xv[kk] = *(const float2*)&Xs [(k + kk) * SX + tn * 2];
          sv[kk] = *(const float2*)&SsT[(k + kk) * SX + tn * 2];
        }
        float4 gv[4], cv[4];
        #pragma unroll
        for (int i = 0; i < 4; ++i) {
          gv[i] = *(const float4*)&Gs[(tm * 4 + i) * SB + k];
          cv[i] = *(const float4*)&Cs[(tm * 4 + i) * SB + k];
        }
        #pragma unroll
        for (int kk = 0; kk < 4; ++kk)
          #pragma unroll
          for (int i = 0; i < 4; ++i) {
            const float g = ((const float*)&gv[i])[kk];
            const float c = ((const float*)&cv[i])[kk];
            accD[i][0] += g * xv[kk].x;
            accD[i][1] += g * xv[kk].y;
            accO[i][0] += c * sv[kk].x;
            accO[i][1] += c * sv[kk].y;
          }
      }
      #pragma unroll
      for (int i = 0; i < 4; ++i) {
        const int l = tm * 4 + i;
        const float e = el[l];
        float2 y;
        y.x = accD[i][0] + e * accO[i][0];
        y.y = accD[i][1] + e * accO[i][1];
        *(float2*)(Yg + (rowB + l) * (Hh * HP) + tn * 2) = y;
      }
    }
    __syncthreads();

    // ---- phase C: S^T[n][p] = exp(Atot)*S^T[n][p] + sum_l B[l][n]*dl[l]*X[l][p] ----
    {
      float acc[4][2] = {};
      #pragma unroll 2
      for (int k = 0; k < 64; k += 4) {
        const float4 dv = *(const float4*)&dl[k];
        float2 xv[4];
        #pragma unroll
        for (int kk = 0; kk < 4; ++kk) {
          xv[kk] = *(const float2*)&Xs[(k + kk) * SX + tn * 2];
          const float d = ((const float*)&dv)[kk];
          xv[kk].x *= d; xv[kk].y *= d;
        }
        float4 bv[4];
        #pragma unroll
        for (int i = 0; i < 4; ++i) bv[i] = *(const float4*)&BsT[(tm * 4 + i) * SB + k];
        #pragma unroll
        for (int kk = 0; kk < 4; ++kk)
          #pragma unroll
          for (int i = 0; i < 4; ++i) {
            const float b = ((const float*)&bv[i])[kk];
            acc[i][0] += b * xv[kk].x;
            acc[i][1] += b * xv[kk].y;
          }
      }
      const float ea = el[63];  // exp(Atot)
      #pragma unroll
      for (int i = 0; i < 4; ++i) {
        const int nn = tm * 4 + i;
        float* s0 = &SsT[nn * SX + tn * 2];
        s0[0] = s0[0] * ea + acc[i][0];
        s0[1] = s0[1] * ea + acc[i][1];
      }
    }
    __syncthreads();
  }
}

} // namespace

extern "C" void kernel_launch(void* const* d_in, const int* in_sizes, int n_in,
                              void* d_out, int out_size, void* d_ws, size_t ws_size,
                              hipStream_t stream) {
  const float* X = (const float*)d_in[0];
  const float* A = (const float*)d_in[1];
  const float* B = (const float*)d_in[2];
  const float* C = (const float*)d_in[3];
  float* Y = (float*)d_out;
  ssd_fused<<<dim3(256), dim3(256), 0, stream>>>(X, A, B, C, Y);
}

// Round 2
// 236.731 us; speedup vs baseline: 2.3553x; 2.3553x over previous
//
#include <hip/hip_runtime.h>

namespace {

typedef __attribute__((ext_vector_type(8))) short short8;
typedef __attribute__((ext_vector_type(4))) float f32x4;

constexpr int Hh = 32;   // heads
constexpr int Ss = 4096; // seq len
constexpr int HP = 64;   // p
constexpr int HN = 64;   // n
constexpr int NCH = 64;  // chunks
constexpr int SB = 72;   // bf16 LDS row stride (elems): rows 16B-aligned, odd dword stride
constexpr int SS = 68;   // fp32 state row stride

__device__ inline unsigned short f2bf(float f) {
  unsigned u = __float_as_uint(f);
  u += 0x7FFFu + ((u >> 16) & 1u);   // RNE
  return (unsigned short)(u >> 16);
}
__device__ inline float bf2f(unsigned short s) {
  return __uint_as_float(((unsigned)s) << 16);
}

// One block = (batch, head, half-of-p): 512 threads (8 waves, 2/SIMD), walks 64
// chunks keeping running state S[p=32][n=64] fp32 in LDS. All 64^3 matmuls on
// bf16 MFMA. Double-buffered bf16 staging (reg-staged: loads issue at chunk
// top, LDS writes after phase C). ~83 KB LDS -> 1 block/CU.
__global__ __launch_bounds__(512, 1)
void ssd_mfma(const float* __restrict__ Xg0, const float* __restrict__ Ag0,
              const float* __restrict__ Bg0, const float* __restrict__ Cg0,
              float* __restrict__ Yg0) {
  __shared__ unsigned short Cs[2][64 * SB];  // C[l][n] bf16
  __shared__ unsigned short Bs[2][64 * SB];  // B[l][n] bf16 (phase A B-operand)
  __shared__ unsigned short BT[2][64 * SB];  // B^T[n][l] bf16 (phase C B-operand)
  __shared__ unsigned short XT[2][32 * SB];  // X^T[p][l] bf16 (phase B B-op, phase C A-op)
  __shared__ unsigned short Gs[64 * SB];     // G[l][s] bf16
  __shared__ float STs[32 * SS];             // state[p][n] fp32, persistent
  __shared__ float ac[2][64];                // A cumsum, double-buffered

  const int tid = threadIdx.x;
  const int blk = blockIdx.x;
  const int ph = blk & 1;
  const int hi = (blk >> 1) & 31;
  const int bi = blk >> 6;

  const float* Xg = Xg0 + ((size_t)bi * Ss * Hh + hi) * HP + ph * 32;
  const float* Bg = Bg0 + ((size_t)bi * Ss * Hh + hi) * HN;
  const float* Cg = Cg0 + ((size_t)bi * Ss * Hh + hi) * HN;
  const float* Ag = Ag0 + (size_t)bi * Ss * Hh + hi;
  float*       Yg = Yg0 + ((size_t)bi * Ss * Hh + hi) * HP + ph * 32;

  const int w = tid >> 6, lane = tid & 63;
  const int lr = lane & 15, lk = lane >> 4;

  for (int i = tid; i < 32 * SS; i += 512) STs[i] = 0.f;

  float4 rb0, rb1, rc0, rc1, rx0;

  auto stage_load = [&](int ci) {
    const size_t rB = (size_t)ci * 64;
    const int r = tid >> 4, c = (tid & 15) * 4;
    rb0 = *(const float4*)(Bg + (rB + r) * (Hh * HN) + c);
    rc0 = *(const float4*)(Cg + (rB + r) * (Hh * HN) + c);
    rb1 = *(const float4*)(Bg + (rB + r + 32) * (Hh * HN) + c);
    rc1 = *(const float4*)(Cg + (rB + r + 32) * (Hh * HN) + c);
    const int rx = tid >> 3, cx = (tid & 7) * 4;
    rx0 = *(const float4*)(Xg + (rB + rx) * (Hh * HP) + cx);
  };

  auto stage_write = [&](int buf) {
    unsigned short* bs = Bs[buf];
    unsigned short* cs = Cs[buf];
    unsigned short* bt = BT[buf];
    unsigned short* xt = XT[buf];
    const int r = tid >> 4, c = (tid & 15) * 4;
    unsigned short b0[4] = {f2bf(rb0.x), f2bf(rb0.y), f2bf(rb0.z), f2bf(rb0.w)};
    unsigned short b1[4] = {f2bf(rb1.x), f2bf(rb1.y), f2bf(rb1.z), f2bf(rb1.w)};
    unsigned short c0[4] = {f2bf(rc0.x), f2bf(rc0.y), f2bf(rc0.z), f2bf(rc0.w)};
    unsigned short c1[4] = {f2bf(rc1.x), f2bf(rc1.y), f2bf(rc1.z), f2bf(rc1.w)};
    *(uint2*)&bs[r * SB + c]        = *(const uint2*)b0;
    *(uint2*)&bs[(r + 32) * SB + c] = *(const uint2*)b1;
    *(uint2*)&cs[r * SB + c]        = *(const uint2*)c0;
    *(uint2*)&cs[(r + 32) * SB + c] = *(const uint2*)c1;
#pragma unroll
    for (int j = 0; j < 4; ++j) {
      bt[(c + j) * SB + r]      = b0[j];
      bt[(c + j) * SB + r + 32] = b1[j];
    }
    const int rx = tid >> 3, cx = (tid & 7) * 4;
    unsigned short x0[4] = {f2bf(rx0.x), f2bf(rx0.y), f2bf(rx0.z), f2bf(rx0.w)};
#pragma unroll
    for (int j = 0; j < 4; ++j) xt[(cx + j) * SB + rx] = x0[j];
  };

  auto a_scan = [&](int ci) {
    if (tid < 64) {
      float a = Ag[(size_t)(ci * 64 + tid) * Hh];
#pragma unroll
      for (int off = 1; off < 64; off <<= 1) {
        float v = __shfl_up(a, off);
        if (tid >= off) a += v;
      }
      ac[ci & 1][tid] = a;
    }
  };

  // prologue: chunk 0
  stage_load(0);
  stage_write(0);
  a_scan(0);

  for (int ci = 0; ci < NCH; ++ci) {
    const int cur = ci & 1;
    __syncthreads();  // B1: staged bufs + ac[cur] visible; prev phase C done

    if (ci + 1 < NCH) {
      stage_load(ci + 1);  // VMEM in flight across the whole chunk
      a_scan(ci + 1);
    }

    const unsigned short* cs = Cs[cur];
    const unsigned short* bs = Bs[cur];
    const unsigned short* bt = BT[cur];
    const unsigned short* xt = XT[cur];
    const float* acv = ac[cur];
    const size_t rB = (size_t)ci * 64;

    // ---- phase A: G = tril(C.B^T) * exp(ac[l]-ac[s]), bf16 into Gs ----
    {
      const int tl = w >> 1;
#pragma unroll
      for (int t = 0; t < 2; ++t) {
        const int ts = (w & 1) * 2 + t;
        if (ts > tl) {
#pragma unroll
          for (int i = 0; i < 4; ++i)
            Gs[(tl * 16 + lk * 4 + i) * SB + ts * 16 + lr] = 0;
        } else {
          f32x4 acc = {0.f, 0.f, 0.f, 0.f};
#pragma unroll
          for (int ks = 0; ks < 2; ++ks) {
            short8 a = *(const short8*)&cs[(tl * 16 + lr) * SB + ks * 32 + lk * 8];
            short8 b = *(const short8*)&bs[(ts * 16 + lr) * SB + ks * 32 + lk * 8];
            acc = __builtin_amdgcn_mfma_f32_16x16x32_bf16(a, b, acc, 0, 0, 0);
          }
          const int gcol = ts * 16 + lr;
          const float acol = acv[gcol];
#pragma unroll
          for (int i = 0; i < 4; ++i) {
            const int grow = tl * 16 + lk * 4 + i;
            float g = (gcol <= grow) ? acc[i] * __expf(acv[grow] - acol) : 0.f;
            Gs[grow * SB + gcol] = f2bf(g);
          }
        }
      }
    }
    __syncthreads();  // B2: Gs ready

    // ---- phase B: Y[l][p] = G.X + exp(ac[l]) * C.S^T ----
    {
      const int tl = w >> 1, tp = w & 1;
      f32x4 aD = {0.f, 0.f, 0.f, 0.f};
      f32x4 aO = {0.f, 0.f, 0.f, 0.f};
#pragma unroll
      for (int ks = 0; ks < 2; ++ks) {
        const int ko = ks * 32 + lk * 8;
        short8 g = *(const short8*)&Gs[(tl * 16 + lr) * SB + ko];
        short8 x = *(const short8*)&xt[(tp * 16 + lr) * SB + ko];
        aD = __builtin_amdgcn_mfma_f32_16x16x32_bf16(g, x, aD, 0, 0, 0);
        short8 c8 = *(const short8*)&cs[(tl * 16 + lr) * SB + ko];
        const float* srow = &STs[(tp * 16 + lr) * SS + ko];
        float4 s0 = *(const float4*)srow;
        float4 s1 = *(const float4*)(srow + 4);
        short8 sb;
        sb[0] = (short)f2bf(s0.x); sb[1] = (short)f2bf(s0.y);
        sb[2] = (short)f2bf(s0.z); sb[3] = (short)f2bf(s0.w);
        sb[4] = (short)f2bf(s1.x); sb[5] = (short)f2bf(s1.y);
        sb[6] = (short)f2bf(s1.z); sb[7] = (short)f2bf(s1.w);
        aO = __builtin_amdgcn_mfma_f32_16x16x32_bf16(c8, sb, aO, 0, 0, 0);
      }
#pragma unroll
      for (int i = 0; i < 4; ++i) {
        const int grow = tl * 16 + lk * 4 + i;
        const float el = __expf(acv[grow]);
        Yg[(rB + grow) * (Hh * HP) + tp * 16 + lr] = aD[i] + el * aO[i];
      }
    }
    __syncthreads();  // B3: old state consumed

    // ---- phase C: S[p][n] = exp(atot)*S + X^T.(dl*B) ----
    {
      const int tp = w >> 2, tn = w & 3;
      const float atot = acv[63];
      f32x4 acc = {0.f, 0.f, 0.f, 0.f};
#pragma unroll
      for (int ks = 0; ks < 2; ++ks) {
        const int ko = ks * 32 + lk * 8;
        short8 a = *(const short8*)&xt[(tp * 16 + lr) * SB + ko];
        short8 braw = *(const short8*)&bt[(tn * 16 + lr) * SB + ko];
        short8 bsc;
#pragma unroll
        for (int j = 0; j < 8; ++j) {
          const float dl = __expf(atot - acv[ko + j]);
          bsc[j] = (short)f2bf(bf2f((unsigned short)braw[j]) * dl);
        }
        acc = __builtin_amdgcn_mfma_f32_16x16x32_bf16(a, bsc, acc, 0, 0, 0);
      }
      const float ea = __expf(atot);
#pragma unroll
      for (int i = 0; i < 4; ++i) {
        const int p = tp * 16 + lk * 4 + i, n = tn * 16 + lr;
        STs[p * SS + n] = STs[p * SS + n] * ea + acc[i];
      }
    }

    if (ci + 1 < NCH) stage_write((ci + 1) & 1);
  }
}

}  // namespace

extern "C" void kernel_launch(void* const* d_in, const int* in_sizes, int n_in,
                              void* d_out, int out_size, void* d_ws, size_t ws_size,
                              hipStream_t stream) {
  const float* X = (const float*)d_in[0];
  const float* A = (const float*)d_in[1];
  const float* B = (const float*)d_in[2];
  const float* C = (const float*)d_in[3];
  float* Y = (float*)d_out;
  (void)d_ws; (void)ws_size; (void)in_sizes; (void)n_in; (void)out_size;
  ssd_mfma<<<dim3(256), dim3(512), 0, stream>>>(X, A, B, C, Y);
}